// Round 7
// baseline (17.520 us; speedup 1.0000x reference)
//
#include <hip/hip_runtime.h>

// VectorQuantizer (per-dim scalar codebooks), B=2048, D=128, K=512.
// out[0] = mean (q-z)^2 ; out[1..] = z + (q - z)  [B,D] row-major.
//
// R7: R3's bit-exact keyed scan (key = rotl1(bits(c-z)) orders by |diff|,
// positive diff wins ties == np.argmin first-min semantics), with:
//  - float2 codebook pairs (plain C++ -> v_pk_add_f32 where profitable)
//  - 256 blocks x 1024 threads (block = (d, half-batch)) -> 256 partials
//  - lean 256-partial reduce kernel (single L2 latency round)

#define B_N 2048
#define D_N 128
#define K_N 512
#define NBLK 256  // (B_N/1024) * D_N

typedef float v2f __attribute__((ext_vector_type(2)));

__device__ __forceinline__ unsigned rotl1(unsigned x) { return (x << 1) | (x >> 31); }
__device__ __forceinline__ unsigned umin3(unsigned a, unsigned b, unsigned c) {
    return min(min(a, b), c);  // -> v_min3_u32
}

__global__ __launch_bounds__(1024) void vq_scan_kernel(
    const float* __restrict__ z,
    const float* __restrict__ cbk,
    float* __restrict__ out,
    float* __restrict__ partial) {
    const int d = blockIdx.x & (D_N - 1);
    const int half = blockIdx.x >> 7;
    const int t = threadIdx.x;
    const int b = (half << 10) + t;

    const float zv = z[b * D_N + d];
    // wave-uniform codebook row read as float2 pairs -> s_load into SGPR pairs
    const v2f* __restrict__ crow2 = (const v2f*)(cbk + d * K_N);

    v2f zv2;
    zv2.x = zv;
    zv2.y = zv;

    unsigned bestA = 0xFFFFFFFFu, bestB = 0xFFFFFFFFu;
    unsigned bestC = 0xFFFFFFFFu, bestD = 0xFFFFFFFFu;

    #pragma unroll
    for (int j = 0; j < K_N / 8; ++j) {  // 4 float2 pairs per iteration
        v2f d0 = crow2[4 * j + 0] - zv2;   // v_pk_add_f32 (neg mod) or 2x v_sub
        v2f d1 = crow2[4 * j + 1] - zv2;
        v2f d2 = crow2[4 * j + 2] - zv2;
        v2f d3 = crow2[4 * j + 3] - zv2;
        bestA = umin3(rotl1(__float_as_uint(d0.x)), rotl1(__float_as_uint(d0.y)), bestA);
        bestB = umin3(rotl1(__float_as_uint(d1.x)), rotl1(__float_as_uint(d1.y)), bestB);
        bestC = umin3(rotl1(__float_as_uint(d2.x)), rotl1(__float_as_uint(d2.y)), bestC);
        bestD = umin3(rotl1(__float_as_uint(d3.x)), rotl1(__float_as_uint(d3.y)), bestD);
    }

    const unsigned best = min(min(bestA, bestB), min(bestC, bestD));
    const float diff = __uint_as_float((best >> 1) | (best << 31));  // fl(q - z)

    out[1 + b * D_N + d] = zv + diff;  // same fp order as reference ST output

    // block partial of (q - z)^2
    float p = diff * diff;
    #pragma unroll
    for (int off = 32; off > 0; off >>= 1) p += __shfl_down(p, off, 64);

    __shared__ float wsum[16];
    const int lane = t & 63;
    const int wid = t >> 6;
    if (lane == 0) wsum[wid] = p;
    __syncthreads();
    if (t == 0) {
        float s = 0.0f;
        #pragma unroll
        for (int w = 0; w < 16; ++w) s += wsum[w];
        partial[blockIdx.x] = s;
    }
}

__global__ __launch_bounds__(256) void vq_reduce_kernel(
    const float* __restrict__ partial, float* __restrict__ out) {
    float p = partial[threadIdx.x];  // NBLK == 256
    #pragma unroll
    for (int off = 32; off > 0; off >>= 1) p += __shfl_down(p, off, 64);
    __shared__ float wsum[4];
    const int lane = threadIdx.x & 63;
    const int wid = threadIdx.x >> 6;
    if (lane == 0) wsum[wid] = p;
    __syncthreads();
    if (threadIdx.x == 0) {
        float s = (wsum[0] + wsum[1]) + (wsum[2] + wsum[3]);
        out[0] = s * (1.0f / (B_N * D_N));
    }
}

extern "C" void kernel_launch(void* const* d_in, const int* in_sizes, int n_in,
                              void* d_out, int out_size, void* d_ws, size_t ws_size,
                              hipStream_t stream) {
    const float* z  = (const float*)d_in[0];
    const float* cb = (const float*)d_in[1];
    float* out = (float*)d_out;
    float* partial = (float*)d_ws;  // NBLK floats, fully overwritten each call

    vq_scan_kernel<<<NBLK, 1024, 0, stream>>>(z, cb, out, partial);
    vq_reduce_kernel<<<1, 256, 0, stream>>>(partial, out);
}

// Round 8
// 16.172 us; speedup vs baseline: 1.0834x; 1.0834x over previous
//
#include <hip/hip_runtime.h>

// VectorQuantizer (per-dim scalar codebooks), B=2048, D=128, K=512.
// out[0] = mean (q-z)^2 ; out[1..] = z + (q - z)  [B,D] row-major.
//
// R8 == R3 (measured best, 16.15 us): bit-exact keyed argmin scan.
//  - block-uniform d -> codebook row loads are scalar (s_load), SGPR operands.
//  - 2.5 VALU ops/code: per 4 codes {4x v_sub_f32, 4x v_alignbit_b32 (rotl1
//    key = (|diff|<<1)|sign, orders by |diff| == order of (z-c)^2, positive
//    diff wins exact ties == np.argmin first-occurrence), 2x v_min3_u32}.
//  - per-block partials + tiny reduce kernel (no atomics, no memset node).
// Sweep evidence (R2/R3/R6/R7): dur is insensitive to scan op count;
// envelope is graph/dispatch overhead (~10-11 us) + ~5 us kernel work.

#define B_N 2048
#define D_N 128
#define K_N 512
#define NBLK ((B_N / 256) * D_N)  // 1024

__device__ __forceinline__ unsigned rotl1(unsigned x) { return (x << 1) | (x >> 31); }
__device__ __forceinline__ unsigned umin3(unsigned a, unsigned b, unsigned c) {
    return min(min(a, b), c);  // -> v_min3_u32
}

__global__ __launch_bounds__(256) void vq_scan_kernel(
    const float* __restrict__ z,
    const float* __restrict__ cbk,
    float* __restrict__ out,
    float* __restrict__ partial) {
    const int d = blockIdx.x & (D_N - 1);
    const int btile = blockIdx.x >> 7;
    const int b = (btile << 8) + threadIdx.x;

    const float zv = z[b * D_N + d];
    const float* __restrict__ crow = cbk + d * K_N;  // wave-uniform -> s_load

    unsigned bestA = 0xFFFFFFFFu, bestB = 0xFFFFFFFFu;

    #pragma unroll
    for (int k0 = 0; k0 < K_N; k0 += 4) {
        float c0 = crow[k0 + 0], c1 = crow[k0 + 1];
        float c2 = crow[k0 + 2], c3 = crow[k0 + 3];
        unsigned q0 = rotl1(__float_as_uint(c0 - zv));
        unsigned q1 = rotl1(__float_as_uint(c1 - zv));
        unsigned q2 = rotl1(__float_as_uint(c2 - zv));
        unsigned q3 = rotl1(__float_as_uint(c3 - zv));
        bestA = umin3(q0, q1, bestA);
        bestB = umin3(q2, q3, bestB);
    }

    unsigned best = min(bestA, bestB);
    float diff = __uint_as_float((best >> 1) | (best << 31));  // fl(q - z)

    out[1 + b * D_N + d] = zv + diff;  // same fp order as reference ST output

    // loss partial: (q - z)^2
    float p = diff * diff;
    #pragma unroll
    for (int off = 32; off > 0; off >>= 1) p += __shfl_down(p, off, 64);

    __shared__ float wsum[4];
    const int lane = threadIdx.x & 63;
    const int wid = threadIdx.x >> 6;
    if (lane == 0) wsum[wid] = p;
    __syncthreads();
    if (threadIdx.x == 0)
        partial[blockIdx.x] = (wsum[0] + wsum[1]) + (wsum[2] + wsum[3]);
}

__global__ __launch_bounds__(256) void vq_reduce_kernel(
    const float* __restrict__ partial, float* __restrict__ out) {
    float p = 0.0f;
    #pragma unroll
    for (int j = 0; j < 4; ++j) p += partial[threadIdx.x + 256 * j];
    #pragma unroll
    for (int off = 32; off > 0; off >>= 1) p += __shfl_down(p, off, 64);

    __shared__ float wsum[4];
    const int lane = threadIdx.x & 63;
    const int wid = threadIdx.x >> 6;
    if (lane == 0) wsum[wid] = p;
    __syncthreads();
    if (threadIdx.x == 0) {
        float s = (wsum[0] + wsum[1]) + (wsum[2] + wsum[3]);
        out[0] = s * (1.0f / (B_N * D_N));
    }
}

extern "C" void kernel_launch(void* const* d_in, const int* in_sizes, int n_in,
                              void* d_out, int out_size, void* d_ws, size_t ws_size,
                              hipStream_t stream) {
    const float* z  = (const float*)d_in[0];
    const float* cb = (const float*)d_in[1];
    float* out = (float*)d_out;
    float* partial = (float*)d_ws;  // NBLK floats, fully overwritten each call

    vq_scan_kernel<<<NBLK, 256, 0, stream>>>(z, cb, out, partial);
    vq_reduce_kernel<<<1, 256, 0, stream>>>(partial, out);
}